// Round 1
// baseline (304.998 us; speedup 1.0000x reference)
//
#include <hip/hip_runtime.h>

// Bilinear sampling: x is (B=128, H=224, W=224, 5) f32 interleaved
// channels [r,g,b,X,Y]; out is (B,224,224,3) f32.
// One thread per output pixel. Gathers are random within a single image
// (~1 MB of x-data) -> L2-resident; XCD swizzle keeps each image's blocks
// on one XCD for L2 locality.

#define HH 224
#define WW 224
#define NB 128

constexpr int PIX_PER_IMG = HH * WW;          // 50176
constexpr int BLOCK       = 256;
constexpr int BLOCKS_PER_IMG = PIX_PER_IMG / BLOCK; // 196 (exact)
constexpr int TOTAL_BLOCKS   = NB * BLOCKS_PER_IMG; // 25088

__global__ __launch_bounds__(BLOCK) void bilinear_kernel(
    const float* __restrict__ x, float* __restrict__ out)
{
    // XCD-aware swizzle: all blocks of image b land on XCD (b & 7).
    // HW round-robins blockIdx.x % 8 across XCDs.
    int i    = blockIdx.x;
    int xcd  = i & 7;
    int slot = i >> 3;                       // 0 .. 3135
    int b    = xcd + 8 * (slot / BLOCKS_PER_IMG);   // image index
    int tile = slot % BLOCKS_PER_IMG;
    int pix  = tile * BLOCK + (int)threadIdx.x;     // pixel within image

    long p = (long)b * PIX_PER_IMG + pix;           // global pixel index
    const float* xp = x + p * 5;
    float X = xp[3];
    float Y = xp[4];

    float fx = floorf(X), fy = floorf(Y);
    float wx = X - fx,    wy = Y - fy;
    float w_tl = (1.f - wx) * (1.f - wy);
    float w_bl = (1.f - wx) * wy;
    float w_tr = wx * (1.f - wy);
    float w_br = wx * wy;

    // Reference: padded index k = clip(f+1 or f+2, 0, 224) (int trunc),
    // img index = k-1, zero-pad outside [0, 224).
    int fxi = (int)fminf(fmaxf(fx + 1.f, 0.f), 224.f) - 1;
    int cxi = (int)fminf(fmaxf(fx + 2.f, 0.f), 224.f) - 1;
    int fyi = (int)fminf(fmaxf(fy + 1.f, 0.f), 224.f) - 1;
    int cyi = (int)fminf(fmaxf(fy + 2.f, 0.f), 224.f) - 1;

    const float* ib = x + (long)b * PIX_PER_IMG * 5;

    float tl0=0.f, tl1=0.f, tl2=0.f;
    float bl0=0.f, bl1=0.f, bl2=0.f;
    float tr0=0.f, tr1=0.f, tr2=0.f;
    float br0=0.f, br1=0.f, br2=0.f;

    {
        bool ok = (fyi >= 0) & (fyi < HH) & (fxi >= 0) & (fxi < WW);
        const float* q = ib + ((long)fyi * WW + fxi) * 5;
        if (ok) { tl0 = q[0]; tl1 = q[1]; tl2 = q[2]; }
    }
    {
        bool ok = (cyi >= 0) & (cyi < HH) & (fxi >= 0) & (fxi < WW);
        const float* q = ib + ((long)cyi * WW + fxi) * 5;
        if (ok) { bl0 = q[0]; bl1 = q[1]; bl2 = q[2]; }
    }
    {
        bool ok = (fyi >= 0) & (fyi < HH) & (cxi >= 0) & (cxi < WW);
        const float* q = ib + ((long)fyi * WW + cxi) * 5;
        if (ok) { tr0 = q[0]; tr1 = q[1]; tr2 = q[2]; }
    }
    {
        bool ok = (cyi >= 0) & (cyi < HH) & (cxi >= 0) & (cxi < WW);
        const float* q = ib + ((long)cyi * WW + cxi) * 5;
        if (ok) { br0 = q[0]; br1 = q[1]; br2 = q[2]; }
    }

    float* o = out + p * 3;
    o[0] = w_tl * tl0 + w_bl * bl0 + w_tr * tr0 + w_br * br0;
    o[1] = w_tl * tl1 + w_bl * bl1 + w_tr * tr1 + w_br * br1;
    o[2] = w_tl * tl2 + w_bl * bl2 + w_tr * tr2 + w_br * br2;
}

extern "C" void kernel_launch(void* const* d_in, const int* in_sizes, int n_in,
                              void* d_out, int out_size, void* d_ws, size_t ws_size,
                              hipStream_t stream) {
    const float* x = (const float*)d_in[0];
    float* out = (float*)d_out;
    bilinear_kernel<<<TOTAL_BLOCKS, BLOCK, 0, stream>>>(x, out);
}